// Round 9
// baseline (173.561 us; speedup 1.0000x reference)
//
#include <hip/hip_runtime.h>
#include <hip/hip_bf16.h>

typedef __attribute__((ext_vector_type(8))) short short8;
typedef __attribute__((ext_vector_type(4))) float f32x4;

constexpr int NB = 4, NT = 512, NE = 1024, NH = 16;
constexpr int NBT = 2048;      // B*T token rows
constexpr int TT = 32;         // attn t-tile

__device__ inline short f2bf(float f) {
    __hip_bfloat16 h = __float2bfloat16(f);
    return __builtin_bit_cast(short, h);
}

// ------- cast+transpose all 3 W: f32 [E][N] -> bf16 [N][E]; Wq/Wv col-perm
// perm: output row jp = (j&15)*64 + (j>>4)   (j = d*16+h -> jp = h*64+d)
__global__ __launch_bounds__(256) void transpose_w_kernel(const float* __restrict__ W0,
                                                          const float* __restrict__ W1,
                                                          const float* __restrict__ W2,
                                                          short* __restrict__ WTall) {
    const float* W = blockIdx.z == 0 ? W0 : (blockIdx.z == 1 ? W1 : W2);
    const bool perm = blockIdx.z < 2;
    short* WT = WTall + (size_t)blockIdx.z * NE * NE;

    __shared__ float tile[64][65];
    const int e0 = blockIdx.y * 64, j0 = blockIdx.x * 64;
    const int el = threadIdx.x & 63, grp = threadIdx.x >> 6;
    for (int i = grp; i < 64; i += 4)
        tile[i][el] = W[(size_t)(e0 + i) * NE + j0 + el];
    __syncthreads();
    for (int it = grp; it < 64; it += 4) {
        int j = j0 + it;
        int jp = perm ? ((j & 15) * 64 + (j >> 4)) : j;
        WT[(size_t)jp * NE + e0 + el] = f2bf(tile[el][it]);
    }
}

// ---------------- MFMA GEMM ------------------------------------------------
// out[r][jp] = sum_e A[r][e] * WT[jp][e] + bias.
// BM x BN tile, BK=64, THREADS/64 waves in (W/2)x2, reg-staged prefetch,
// XOR-swizzled LDS. A_F32: A read as f32 + inline bf16 cvt.
// ZT_DUAL: grid-x spans 2*NE; c0>=NE half computes with SWAPPED mfma operands
// -> D[jp][token], writes transposed Zt[jp][token] (+bias1).
template <int BM, int BN, int THREADS, int LOG_GX, bool A_F32, bool ZT_DUAL, bool PERM_BIAS, bool OUT_BF16>
__global__ __launch_bounds__(THREADS) void mfma_gemm_kernel(const void* __restrict__ Xv,
                                                            const short* __restrict__ WT,
                                                            const float* __restrict__ bias0,
                                                            const float* __restrict__ bias1,
                                                            void* __restrict__ out0,
                                                            short* __restrict__ outZt) {
    constexpr int WAVES = THREADS / 64;
    constexpr int WAVE_M = BM / (WAVES / 2), WAVE_N = BN / 2;
    constexpr int MR = WAVE_M / 16, NR = WAVE_N / 16;
    constexpr int RDA = BM * 8 / THREADS, RDB = BN * 8 / THREADS;

    __shared__ short As[BM * 64];
    __shared__ short Bs[BN * 64];
    const int tid = threadIdx.x;
    const int lane = tid & 63, wid = tid >> 6;

    // bijective XCD swizzle (nwg % 8 == 0)
    const int nwg = (1 << LOG_GX) * gridDim.y;
    const int bid = blockIdx.y * (1 << LOG_GX) + blockIdx.x;
    const int swz = (bid & 7) * (nwg >> 3) + (bid >> 3);
    const int r0 = (swz >> LOG_GX) * BM;
    const int c0 = (swz & ((1 << LOG_GX) - 1)) * BN;
    const int wr = (wid >> 1) * WAVE_M, wc = (wid & 1) * WAVE_N;
    const bool isZ = ZT_DUAL && (c0 >= NE);

    f32x4 acc[MR][NR];
#pragma unroll
    for (int m = 0; m < MR; m++)
#pragma unroll
        for (int n = 0; n < NR; n++) acc[m][n] = (f32x4){0.f, 0.f, 0.f, 0.f};

    short8 pfA[RDA], pfB[RDB];
    auto load_tiles = [&](int k0) {
#pragma unroll
        for (int rd = 0; rd < RDA; rd++) {
            int slot = rd * (THREADS * 16) + tid * 16;
            int row  = slot >> 7;
            int c    = ((slot >> 4) & 7) ^ (row & 7);
            if (A_F32) {
                const float* xa = (const float*)Xv + (size_t)(r0 + row) * NE + k0 + c * 8;
                float4 a = *(const float4*)xa, b = *(const float4*)(xa + 4);
                short8 v;
                v[0] = f2bf(a.x); v[1] = f2bf(a.y); v[2] = f2bf(a.z); v[3] = f2bf(a.w);
                v[4] = f2bf(b.x); v[5] = f2bf(b.y); v[6] = f2bf(b.z); v[7] = f2bf(b.w);
                pfA[rd] = v;
            } else {
                pfA[rd] = *(const short8*)((const short*)Xv + (size_t)(r0 + row) * NE + k0 + c * 8);
            }
        }
#pragma unroll
        for (int rd = 0; rd < RDB; rd++) {
            int slot = rd * (THREADS * 16) + tid * 16;
            int row  = slot >> 7;
            int c    = ((slot >> 4) & 7) ^ (row & 7);
            pfB[rd] = *(const short8*)(WT + (size_t)(c0 + row) * NE + k0 + c * 8);
        }
    };

    load_tiles(0);
    for (int k0 = 0; k0 < NE; k0 += 64) {
        __syncthreads();
#pragma unroll
        for (int rd = 0; rd < RDA; rd++)
            *(short8*)((char*)As + rd * (THREADS * 16) + tid * 16) = pfA[rd];
#pragma unroll
        for (int rd = 0; rd < RDB; rd++)
            *(short8*)((char*)Bs + rd * (THREADS * 16) + tid * 16) = pfB[rd];
        __syncthreads();
        if (k0 + 64 < NE) load_tiles(k0 + 64);

#pragma unroll
        for (int kk = 0; kk < 2; kk++) {
            short8 af[MR], bf[NR];
            const int cidx = kk * 4 + (lane >> 4);
#pragma unroll
            for (int m = 0; m < MR; m++) {
                int row = wr + m * 16 + (lane & 15);
                af[m] = *(const short8*)((char*)As + row * 128 + ((cidx ^ (row & 7)) * 16));
            }
#pragma unroll
            for (int n = 0; n < NR; n++) {
                int row = wc + n * 16 + (lane & 15);
                bf[n] = *(const short8*)((char*)Bs + row * 128 + ((cidx ^ (row & 7)) * 16));
            }
            if (isZ) {
                // swapped operands: D[jp][token]
#pragma unroll
                for (int m = 0; m < MR; m++)
#pragma unroll
                    for (int n = 0; n < NR; n++)
                        acc[m][n] = __builtin_amdgcn_mfma_f32_16x16x32_bf16(bf[n], af[m], acc[m][n], 0, 0, 0);
            } else {
#pragma unroll
                for (int m = 0; m < MR; m++)
#pragma unroll
                    for (int n = 0; n < NR; n++)
                        acc[m][n] = __builtin_amdgcn_mfma_f32_16x16x32_bf16(af[m], bf[n], acc[m][n], 0, 0, 0);
            }
        }
    }

    if (isZ) {
        // acc[m][n]: C-row = jp-local = wc + n*16 + (lane>>4)*4 + r
        //            C-col = token    = wr + m*16 + (lane&15)
        const int cb = c0 - NE;
        const int tok = r0 + wr + (lane & 15);
#pragma unroll
        for (int m = 0; m < MR; m++)
#pragma unroll
            for (int n = 0; n < NR; n++)
#pragma unroll
                for (int r = 0; r < 4; r++) {
                    int jp = cb + wc + n * 16 + (lane >> 4) * 4 + r;
                    float bb = bias1[(jp & 63) * 16 + (jp >> 6)];
                    outZt[(size_t)jp * NBT + tok + m * 16] = f2bf(acc[m][n][r] + bb);
                }
    } else {
        short* outS = (short*)out0;
        float* outF = (float*)out0;
#pragma unroll
        for (int m = 0; m < MR; m++)
#pragma unroll
            for (int n = 0; n < NR; n++) {
                int lc   = c0 + wc + n * 16 + (lane & 15);
                int bsrc = PERM_BIAS ? ((lc & 63) * 16 + (lc >> 6)) : lc;
                float bb = bias0[bsrc];
#pragma unroll
                for (int r = 0; r < 4; r++) {
                    int row = r0 + wr + m * 16 + (lane >> 4) * 4 + r;
                    float val = acc[m][n][r] + bb;
                    if (OUT_BF16) outS[(size_t)row * NE + lc] = f2bf(val);
                    else          outF[(size_t)row * NE + lc] = val;
                }
            }
    }
}

// ---------------- MFMA windowed attention ----------------------------------
// Y bf16 [BT][NE] head-major (Q and K rows); Zt bf16 [NE][BT] (V transposed).
// Block = (t-tile 32, h, b). S = Q K^T over the 96-row window via MFMA,
// banded softmax, O = P V via MFMA with V^T from Zt. Out Mb[BT][NE].
__global__ __launch_bounds__(256) void attn_kernel(const short* __restrict__ Yb,
                                                   const short* __restrict__ Zt,
                                                   short* __restrict__ Mb) {
    __shared__ __align__(16) short KS[96][64];    // XOR-swizzled 16B chunks
    __shared__ __align__(16) short VT[64][96];    // [d][ws] linear
    __shared__ __align__(16) float SL[32][100];   // scores
    __shared__ __align__(16) short PL[32][104];   // probs bf16, zeroed outside band
    __shared__ float RED[32][17];                 // 0..7 max, 8..15 sum, 16 inv

    const int t0 = blockIdx.x * TT;
    const int h  = blockIdx.y;
    const int b  = blockIdx.z;
    const int tid = threadIdx.x;
    const int lane = tid & 63, wid = tid >> 6;

    // zero PL (banded writes later): 32*104/8 = 416 short8
    for (int u = tid; u < 416; u += 256)
        *(short8*)((short*)PL + u * 8) = (short8){0, 0, 0, 0, 0, 0, 0, 0};

    // stage K (= Y rows, also Q): 96 rows x 8 chunks, XOR-swizzled
    for (int u = tid; u < 768; u += 256) {
        int r = u >> 3, c = u & 7;
        int ts = t0 - 32 + r;
        ts = ts < 0 ? 0 : (ts > NT - 1 ? NT - 1 : ts);
        short8 kv = *(const short8*)(Yb + ((size_t)b * NT + ts) * NE + h * 64 + c * 8);
        *(short8*)&KS[r][(c ^ (r & 7)) * 8] = kv;
    }
    // stage V^T from Zt rows: 64 d-rows x 12 chunks of 8 (ws in [0,96))
    {
        const int d = tid >> 2, cbase = (tid & 3) * 3;
        const short* zr = Zt + (size_t)(h * 64 + d) * NBT + b * NT;
#pragma unroll
        for (int i = 0; i < 3; i++) {
            int ch = cbase + i;
            int s0 = t0 - 32 + ch * 8;
            short8 v;
            if (s0 >= 0 && s0 <= NT - 8) {
                v = *(const short8*)(zr + s0);
            } else {
#pragma unroll
                for (int j = 0; j < 8; j++) {
                    int ss = s0 + j;
                    ss = ss < 0 ? 0 : (ss > NT - 1 ? NT - 1 : ss);
                    v[j] = zr[ss];
                }
            }
            *(short8*)&VT[d][ch * 8] = v;
        }
    }
    __syncthreads();

    // QK^T: wave wid: m-frag mq = wid>>1, n-frags ntrio..+2 (s-cols)
    {
        const int mq = wid >> 1, ntrio = (wid & 1) * 3;
        f32x4 sacc[3];
#pragma unroll
        for (int ni = 0; ni < 3; ni++) sacc[ni] = (f32x4){0.f, 0.f, 0.f, 0.f};
#pragma unroll
        for (int ks = 0; ks < 2; ks++) {
            const int cidx = ks * 4 + (lane >> 4);
            int qrow = 32 + mq * 16 + (lane & 15);
            short8 af = *(const short8*)((char*)KS + qrow * 128 + ((cidx ^ (qrow & 7)) * 16));
#pragma unroll
            for (int ni = 0; ni < 3; ni++) {
                int srow = (ntrio + ni) * 16 + (lane & 15);
                short8 bf = *(const short8*)((char*)KS + srow * 128 + ((cidx ^ (srow & 7)) * 16));
                sacc[ni] = __builtin_amdgcn_mfma_f32_16x16x32_bf16(af, bf, sacc[ni], 0, 0, 0);
            }
        }
#pragma unroll
        for (int ni = 0; ni < 3; ni++)
#pragma unroll
            for (int r = 0; r < 4; r++)
                SL[mq * 16 + (lane >> 4) * 4 + r][(ntrio + ni) * 16 + (lane & 15)] =
                    sacc[ni][r] * 0.03125f;   // 1/sqrt(E)
    }
    __syncthreads();

    // banded softmax: thread (tl, oct) handles w = oct*8..+8, s = tl + w
    {
        const int tl = tid & (TT - 1), oct = tid >> 5;
        float sv[8];
#pragma unroll
        for (int wi = 0; wi < 8; wi++) sv[wi] = SL[tl][tl + oct * 8 + wi];
        float lmax = sv[0];
#pragma unroll
        for (int wi = 1; wi < 8; wi++) lmax = fmaxf(lmax, sv[wi]);
        RED[tl][oct] = lmax;
        __syncthreads();
        float gmax = RED[tl][0];
#pragma unroll
        for (int i = 1; i < 8; i++) gmax = fmaxf(gmax, RED[tl][i]);
        float lsum = 0.f;
#pragma unroll
        for (int wi = 0; wi < 8; wi++) {
            float e = __expf(sv[wi] - gmax);
            PL[tl][tl + oct * 8 + wi] = f2bf(e);
            lsum += e;
        }
        RED[tl][8 + oct] = lsum;
        __syncthreads();
        float gsum = RED[tl][8];
#pragma unroll
        for (int i = 9; i < 16; i++) gsum += RED[tl][i];
        if (oct == 0) RED[tl][16] = 1.0f / gsum;
    }
    __syncthreads();

    // PV: wave wid: m-frag mp = wid>>1 (rows), n-frags npair..+1 (d-cols)
    {
        const int mp = wid >> 1, npair = (wid & 1) * 2;
        f32x4 oacc[2];
#pragma unroll
        for (int ni = 0; ni < 2; ni++) oacc[ni] = (f32x4){0.f, 0.f, 0.f, 0.f};
#pragma unroll
        for (int ks = 0; ks < 3; ks++) {   // K = 96
            int prow = mp * 16 + (lane & 15);
            short8 pa = *(const short8*)((char*)PL + prow * 208 + ks * 64 + (lane >> 4) * 16);
#pragma unroll
            for (int ni = 0; ni < 2; ni++) {
                int d = (npair + ni) * 16 + (lane & 15);
                short8 bv = *(const short8*)((char*)VT + d * 192 + ks * 64 + (lane >> 4) * 16);
                oacc[ni] = __builtin_amdgcn_mfma_f32_16x16x32_bf16(pa, bv, oacc[ni], 0, 0, 0);
            }
        }
#pragma unroll
        for (int ni = 0; ni < 2; ni++) {
            int d = (npair + ni) * 16 + (lane & 15);
#pragma unroll
            for (int r = 0; r < 4; r++) {
                int tl = mp * 16 + (lane >> 4) * 4 + r;
                float inv = RED[tl][16];
                Mb[((size_t)b * NT + t0 + tl) * NE + h * 64 + d] = f2bf(oacc[ni][r] * inv);
            }
        }
    }
}

// ---------------------------------------------------------------------------
extern "C" void kernel_launch(void* const* d_in, const int* in_sizes, int n_in,
                              void* d_out, int out_size, void* d_ws, size_t ws_size,
                              hipStream_t stream) {
    const float* x  = (const float*)d_in[0];
    // d_in[1] = position_mask: unused (window gather computed analytically)
    const float* Wq = (const float*)d_in[2];
    const float* bq = (const float*)d_in[3];
    const float* Wv = (const float*)d_in[4];
    const float* bv = (const float*)d_in[5];
    const float* Wo = (const float*)d_in[6];
    const float* bo = (const float*)d_in[7];
    float* outp = (float*)d_out;

    // ws: WTa 6M (Wq,Wv,Wo) | Yb 4M | Zt 4M | Mb 4M
    char* wsb = (char*)d_ws;
    short* WTa = (short*)(wsb);
    short* Yb  = (short*)(wsb + (6u << 20));
    short* Zt  = (short*)(wsb + (10u << 20));
    short* Mb  = (short*)(wsb + (14u << 20));
    short* WTo = WTa + 2 * (size_t)NE * NE;

    transpose_w_kernel<<<dim3(16, 16, 3), 256, 0, stream>>>(Wq, Wv, Wo, WTa);

    // fused Q/V projection: 128x128 tile, 8 waves; grid (16,16); Z half -> Zt
    mfma_gemm_kernel<128, 128, 512, 4, true, true, true, true>
        <<<dim3(2 * NE / 128, NBT / 128), 512, 0, stream>>>(x, WTa, bq, bv, Yb, Zt);

    attn_kernel<<<dim3(NT / TT, NH, NB), 256, 0, stream>>>(Yb, Zt, Mb);

    // output projection: 64x128 tile, 4 waves -> grid (8,32)
    mfma_gemm_kernel<64, 128, 256, 3, false, false, false, false>
        <<<dim3(NE / 128, NBT / 64), 256, 0, stream>>>(Mb, WTo, bo, nullptr, (void*)outp, nullptr);
}

// Round 10
// 156.535 us; speedup vs baseline: 1.1088x; 1.1088x over previous
//
#include <hip/hip_runtime.h>
#include <hip/hip_bf16.h>

typedef __attribute__((ext_vector_type(8))) short short8;
typedef __attribute__((ext_vector_type(4))) float f32x4;

constexpr int NB = 4, NT = 512, NE = 1024, NH = 16;
constexpr int NBT = 2048;      // B*T token rows
constexpr int TT = 32;         // attn t-tile

__device__ inline short f2bf(float f) {
    __hip_bfloat16 h = __float2bfloat16(f);
    return __builtin_bit_cast(short, h);
}

// async global->LDS DMA, 16B per lane; LDS dest = wave-uniform base + lane*16
#define GLOAD16(g, l) \
    __builtin_amdgcn_global_load_lds((const __attribute__((address_space(1))) void*)(g), \
                                     (__attribute__((address_space(3))) void*)(l), 16, 0, 0)

// ------- prep: z<3: cast+transpose W (f32 [E][N] -> bf16 [N][E], Wq/Wv col-perm)
//               z==3: cast x -> bf16 row-major
__global__ __launch_bounds__(256) void prep_kernel(const float* __restrict__ x,
                                                   const float* __restrict__ W0,
                                                   const float* __restrict__ W1,
                                                   const float* __restrict__ W2,
                                                   short* __restrict__ WTall,
                                                   short* __restrict__ Xb) {
    if (blockIdx.z == 3) {
        const int gid = blockIdx.y * 16 + blockIdx.x;          // 0..255
        size_t base = (size_t)gid * 8192 + threadIdx.x * 8;
#pragma unroll
        for (int it = 0; it < 4; it++) {
            const float4* p = (const float4*)(x + base + it * 2048);
            float4 a = p[0], b = p[1];
            short8 v;
            v[0] = f2bf(a.x); v[1] = f2bf(a.y); v[2] = f2bf(a.z); v[3] = f2bf(a.w);
            v[4] = f2bf(b.x); v[5] = f2bf(b.y); v[6] = f2bf(b.z); v[7] = f2bf(b.w);
            *(short8*)(Xb + base + it * 2048) = v;
        }
        return;
    }
    const float* W = blockIdx.z == 0 ? W0 : (blockIdx.z == 1 ? W1 : W2);
    const bool perm = blockIdx.z < 2;
    short* WT = WTall + (size_t)blockIdx.z * NE * NE;

    __shared__ float tile[64][65];
    const int e0 = blockIdx.y * 64, j0 = blockIdx.x * 64;
    const int el = threadIdx.x & 63, grp = threadIdx.x >> 6;
    for (int i = grp; i < 64; i += 4)
        tile[i][el] = W[(size_t)(e0 + i) * NE + j0 + el];
    __syncthreads();
    for (int it = grp; it < 64; it += 4) {
        int j = j0 + it;
        int jp = perm ? ((j & 15) * 64 + (j >> 4)) : j;
        WT[(size_t)jp * NE + e0 + el] = f2bf(tile[el][it]);
    }
}

// ---------------- MFMA GEMM (global_load_lds + dbuf, 1 barrier/K-step) -----
// out[r][jp] = sum_e A[r][e] * WT[jp][e] + bias.  A,WT bf16.
// LDS layout: row-major [rows][64] bf16, 16B chunk cp at row holds global
// chunk cp^(row&7) (inverse-swizzled SOURCE, linear dest; read applies XOR).
// ZT_DUAL: grid-x spans 2*NE; c0>=NE half uses SWAPPED mfma operands ->
// D[jp][token], writes transposed Zt[jp][token] (+bias1, perm'd).
template <int BM, int BN, int THREADS, int LOG_GX, bool ZT_DUAL, bool PERM_BIAS, bool OUT_BF16>
__global__ __launch_bounds__(THREADS) void mfma_gemm_kernel(const short* __restrict__ A,
                                                            const short* __restrict__ WT,
                                                            const float* __restrict__ bias0,
                                                            const float* __restrict__ bias1,
                                                            void* __restrict__ out0,
                                                            short* __restrict__ outZt) {
    constexpr int WAVES = THREADS / 64;
    constexpr int WAVE_M = BM / (WAVES / 2), WAVE_N = BN / 2;
    constexpr int MR = WAVE_M / 16, NR = WAVE_N / 16;
    constexpr int ASZ = BM * 64, BSZ = BN * 64;           // shorts
    constexpr int SWA = BM * 128 / (THREADS * 16);        // A DMA sweeps
    constexpr int SWB = BN * 128 / (THREADS * 16);        // B DMA sweeps

    __shared__ __align__(16) short LB[2][ASZ + BSZ];
    const int tid = threadIdx.x;
    const int lane = tid & 63, wid = tid >> 6;

    // bijective XCD swizzle (nwg % 8 == 0)
    const int nwg = (1 << LOG_GX) * gridDim.y;
    const int bid = blockIdx.y * (1 << LOG_GX) + blockIdx.x;
    const int swz = (bid & 7) * (nwg >> 3) + (bid >> 3);
    const int r0 = (swz >> LOG_GX) * BM;
    const int c0 = (swz & ((1 << LOG_GX) - 1)) * BN;
    const int wr = (wid >> 1) * WAVE_M, wc = (wid & 1) * WAVE_N;
    const bool isZ = ZT_DUAL && (c0 >= NE);

    f32x4 acc[MR][NR];
#pragma unroll
    for (int m = 0; m < MR; m++)
#pragma unroll
        for (int n = 0; n < NR; n++) acc[m][n] = (f32x4){0.f, 0.f, 0.f, 0.f};

    // issue DMA for one K-tile into buffer `buf`
    auto stage = [&](int buf, int k0) {
        char* Ab = (char*)&LB[buf][0];
        char* Bb = (char*)&LB[buf][ASZ];
#pragma unroll
        for (int s = 0; s < SWA; s++) {
            int wb  = s * (THREADS * 16) + wid * 1024;    // wave-uniform LDS byte base
            int off = wb + lane * 16;                     // this lane's dest
            int row = off >> 7;
            int c   = ((off >> 4) & 7) ^ (row & 7);       // pre-swizzled source chunk
            GLOAD16(A + (size_t)(r0 + row) * NE + k0 + c * 8, Ab + wb);
        }
#pragma unroll
        for (int s = 0; s < SWB; s++) {
            int wb  = s * (THREADS * 16) + wid * 1024;
            int off = wb + lane * 16;
            int row = off >> 7;
            int c   = ((off >> 4) & 7) ^ (row & 7);
            GLOAD16(WT + (size_t)(c0 + row) * NE + k0 + c * 8, Bb + wb);
        }
    };

    stage(0, 0);
    __syncthreads();   // implicit vmcnt(0) drain: tile 0 resident

    int cur = 0;
    for (int k0 = 0; k0 < NE; k0 += 64) {
        if (k0 + 64 < NE) stage(cur ^ 1, k0 + 64);   // DMA next tile under compute
        const char* Ab = (const char*)&LB[cur][0];
        const char* Bb = (const char*)&LB[cur][ASZ];
#pragma unroll
        for (int kk = 0; kk < 2; kk++) {
            short8 af[MR], bf[NR];
            const int cidx = kk * 4 + (lane >> 4);
#pragma unroll
            for (int m = 0; m < MR; m++) {
                int row = wr + m * 16 + (lane & 15);
                af[m] = *(const short8*)(Ab + row * 128 + ((cidx ^ (row & 7)) * 16));
            }
#pragma unroll
            for (int n = 0; n < NR; n++) {
                int row = wc + n * 16 + (lane & 15);
                bf[n] = *(const short8*)(Bb + row * 128 + ((cidx ^ (row & 7)) * 16));
            }
            if (isZ) {
#pragma unroll
                for (int m = 0; m < MR; m++)
#pragma unroll
                    for (int n = 0; n < NR; n++)
                        acc[m][n] = __builtin_amdgcn_mfma_f32_16x16x32_bf16(bf[n], af[m], acc[m][n], 0, 0, 0);
            } else {
#pragma unroll
                for (int m = 0; m < MR; m++)
#pragma unroll
                    for (int n = 0; n < NR; n++)
                        acc[m][n] = __builtin_amdgcn_mfma_f32_16x16x32_bf16(af[m], bf[n], acc[m][n], 0, 0, 0);
            }
        }
        __syncthreads();   // drains vmcnt(0) (next tile landed) + all reads done
        cur ^= 1;
    }

    if (isZ) {
        // acc[m][n]: C-row = jp-local = wc + n*16 + (lane>>4)*4 + r
        //            C-col = token    = wr + m*16 + (lane&15)
        const int cb = c0 - NE;
        const int tok = r0 + wr + (lane & 15);
#pragma unroll
        for (int m = 0; m < MR; m++)
#pragma unroll
            for (int n = 0; n < NR; n++)
#pragma unroll
                for (int r = 0; r < 4; r++) {
                    int jp = cb + wc + n * 16 + (lane >> 4) * 4 + r;
                    float bb = bias1[(jp & 63) * 16 + (jp >> 6)];
                    outZt[(size_t)jp * NBT + tok + m * 16] = f2bf(acc[m][n][r] + bb);
                }
    } else {
        short* outS = (short*)out0;
        float* outF = (float*)out0;
#pragma unroll
        for (int m = 0; m < MR; m++)
#pragma unroll
            for (int n = 0; n < NR; n++) {
                int lc   = c0 + wc + n * 16 + (lane & 15);
                int bsrc = PERM_BIAS ? ((lc & 63) * 16 + (lc >> 6)) : lc;
                float bb = bias0[bsrc];
#pragma unroll
                for (int r = 0; r < 4; r++) {
                    int row = r0 + wr + m * 16 + (lane >> 4) * 4 + r;
                    float val = acc[m][n][r] + bb;
                    if (OUT_BF16) outS[(size_t)row * NE + lc] = f2bf(val);
                    else          outF[(size_t)row * NE + lc] = val;
                }
            }
    }
}

// ---------------- MFMA windowed attention (unchanged, verified) ------------
__global__ __launch_bounds__(256) void attn_kernel(const short* __restrict__ Yb,
                                                   const short* __restrict__ Zt,
                                                   short* __restrict__ Mb) {
    __shared__ __align__(16) short KS[96][64];    // XOR-swizzled 16B chunks
    __shared__ __align__(16) short VT[64][96];    // [d][ws] linear
    __shared__ __align__(16) float SL[32][100];   // scores
    __shared__ __align__(16) short PL[32][104];   // probs bf16, zeroed outside band
    __shared__ float RED[32][17];                 // 0..7 max, 8..15 sum, 16 inv

    const int t0 = blockIdx.x * TT;
    const int h  = blockIdx.y;
    const int b  = blockIdx.z;
    const int tid = threadIdx.x;
    const int lane = tid & 63, wid = tid >> 6;

    for (int u = tid; u < 416; u += 256)
        *(short8*)((short*)PL + u * 8) = (short8){0, 0, 0, 0, 0, 0, 0, 0};

    for (int u = tid; u < 768; u += 256) {
        int r = u >> 3, c = u & 7;
        int ts = t0 - 32 + r;
        ts = ts < 0 ? 0 : (ts > NT - 1 ? NT - 1 : ts);
        short8 kv = *(const short8*)(Yb + ((size_t)b * NT + ts) * NE + h * 64 + c * 8);
        *(short8*)&KS[r][(c ^ (r & 7)) * 8] = kv;
    }
    {
        const int d = tid >> 2, cbase = (tid & 3) * 3;
        const short* zr = Zt + (size_t)(h * 64 + d) * NBT + b * NT;
#pragma unroll
        for (int i = 0; i < 3; i++) {
            int ch = cbase + i;
            int s0 = t0 - 32 + ch * 8;
            short8 v;
            if (s0 >= 0 && s0 <= NT - 8) {
                v = *(const short8*)(zr + s0);
            } else {
#pragma unroll
                for (int j = 0; j < 8; j++) {
                    int ss = s0 + j;
                    ss = ss < 0 ? 0 : (ss > NT - 1 ? NT - 1 : ss);
                    v[j] = zr[ss];
                }
            }
            *(short8*)&VT[d][ch * 8] = v;
        }
    }
    __syncthreads();

    {
        const int mq = wid >> 1, ntrio = (wid & 1) * 3;
        f32x4 sacc[3];
#pragma unroll
        for (int ni = 0; ni < 3; ni++) sacc[ni] = (f32x4){0.f, 0.f, 0.f, 0.f};
#pragma unroll
        for (int ks = 0; ks < 2; ks++) {
            const int cidx = ks * 4 + (lane >> 4);
            int qrow = 32 + mq * 16 + (lane & 15);
            short8 af = *(const short8*)((char*)KS + qrow * 128 + ((cidx ^ (qrow & 7)) * 16));
#pragma unroll
            for (int ni = 0; ni < 3; ni++) {
                int srow = (ntrio + ni) * 16 + (lane & 15);
                short8 bf = *(const short8*)((char*)KS + srow * 128 + ((cidx ^ (srow & 7)) * 16));
                sacc[ni] = __builtin_amdgcn_mfma_f32_16x16x32_bf16(af, bf, sacc[ni], 0, 0, 0);
            }
        }
#pragma unroll
        for (int ni = 0; ni < 3; ni++)
#pragma unroll
            for (int r = 0; r < 4; r++)
                SL[mq * 16 + (lane >> 4) * 4 + r][(ntrio + ni) * 16 + (lane & 15)] =
                    sacc[ni][r] * 0.03125f;   // 1/sqrt(E)
    }
    __syncthreads();

    {
        const int tl = tid & (TT - 1), oct = tid >> 5;
        float sv[8];
#pragma unroll
        for (int wi = 0; wi < 8; wi++) sv[wi] = SL[tl][tl + oct * 8 + wi];
        float lmax = sv[0];
#pragma unroll
        for (int wi = 1; wi < 8; wi++) lmax = fmaxf(lmax, sv[wi]);
        RED[tl][oct] = lmax;
        __syncthreads();
        float gmax = RED[tl][0];
#pragma unroll
        for (int i = 1; i < 8; i++) gmax = fmaxf(gmax, RED[tl][i]);
        float lsum = 0.f;
#pragma unroll
        for (int wi = 0; wi < 8; wi++) {
            float e = __expf(sv[wi] - gmax);
            PL[tl][tl + oct * 8 + wi] = f2bf(e);
            lsum += e;
        }
        RED[tl][8 + oct] = lsum;
        __syncthreads();
        float gsum = RED[tl][8];
#pragma unroll
        for (int i = 9; i < 16; i++) gsum += RED[tl][i];
        if (oct == 0) RED[tl][16] = 1.0f / gsum;
    }
    __syncthreads();

    {
        const int mp = wid >> 1, npair = (wid & 1) * 2;
        f32x4 oacc[2];
#pragma unroll
        for (int ni = 0; ni < 2; ni++) oacc[ni] = (f32x4){0.f, 0.f, 0.f, 0.f};
#pragma unroll
        for (int ks = 0; ks < 3; ks++) {   // K = 96
            int prow = mp * 16 + (lane & 15);
            short8 pa = *(const short8*)((char*)PL + prow * 208 + ks * 64 + (lane >> 4) * 16);
#pragma unroll
            for (int ni = 0; ni < 2; ni++) {
                int d = (npair + ni) * 16 + (lane & 15);
                short8 bv = *(const short8*)((char*)VT + d * 192 + ks * 64 + (lane >> 4) * 16);
                oacc[ni] = __builtin_amdgcn_mfma_f32_16x16x32_bf16(pa, bv, oacc[ni], 0, 0, 0);
            }
        }
#pragma unroll
        for (int ni = 0; ni < 2; ni++) {
            int d = (npair + ni) * 16 + (lane & 15);
#pragma unroll
            for (int r = 0; r < 4; r++) {
                int tl = mp * 16 + (lane >> 4) * 4 + r;
                float inv = RED[tl][16];
                Mb[((size_t)b * NT + t0 + tl) * NE + h * 64 + d] = f2bf(oacc[ni][r] * inv);
            }
        }
    }
}

// ---------------------------------------------------------------------------
extern "C" void kernel_launch(void* const* d_in, const int* in_sizes, int n_in,
                              void* d_out, int out_size, void* d_ws, size_t ws_size,
                              hipStream_t stream) {
    const float* x  = (const float*)d_in[0];
    // d_in[1] = position_mask: unused (window gather computed analytically)
    const float* Wq = (const float*)d_in[2];
    const float* bq = (const float*)d_in[3];
    const float* Wv = (const float*)d_in[4];
    const float* bv = (const float*)d_in[5];
    const float* Wo = (const float*)d_in[6];
    const float* bo = (const float*)d_in[7];
    float* outp = (float*)d_out;

    // ws: WTa 6M (Wq,Wv,Wo) | Xb 4M | Yb 4M | Zt 4M | Mb 4M
    char* wsb = (char*)d_ws;
    short* WTa = (short*)(wsb);
    short* Xb  = (short*)(wsb + (6u << 20));
    short* Yb  = (short*)(wsb + (10u << 20));
    short* Zt  = (short*)(wsb + (14u << 20));
    short* Mb  = (short*)(wsb + (18u << 20));
    short* WTo = WTa + 2 * (size_t)NE * NE;

    prep_kernel<<<dim3(16, 16, 4), 256, 0, stream>>>(x, Wq, Wv, Wo, WTa, Xb);

    // fused Q/V projection: 128x128 tile, 8 waves; grid (16,16); Z half -> Zt
    mfma_gemm_kernel<128, 128, 512, 4, true, true, true>
        <<<dim3(2 * NE / 128, NBT / 128), 512, 0, stream>>>(Xb, WTa, bq, bv, Yb, Zt);

    attn_kernel<<<dim3(NT / TT, NH, NB), 256, 0, stream>>>(Yb, Zt, Mb);

    // output projection: 64x128 tile, 4 waves -> grid (8,32)
    mfma_gemm_kernel<64, 128, 256, 3, false, false, false>
        <<<dim3(NE / 128, NBT / 64), 256, 0, stream>>>(Mb, WTo, bo, nullptr, (void*)outp, nullptr);
}

// Round 11
// 151.748 us; speedup vs baseline: 1.1437x; 1.0315x over previous
//
#include <hip/hip_runtime.h>
#include <hip/hip_bf16.h>

typedef __attribute__((ext_vector_type(8))) short short8;
typedef __attribute__((ext_vector_type(4))) float f32x4;

constexpr int NB = 4, NT = 512, NE = 1024, NH = 16;
constexpr int NBT = 2048;      // B*T token rows
constexpr int TT = 32;         // attn t-tile

__device__ inline short f2bf(float f) {
    __hip_bfloat16 h = __float2bfloat16(f);
    return __builtin_bit_cast(short, h);
}

// async global->LDS DMA, 16B per lane; LDS dest = wave-uniform base + lane*16
#define GLOAD16(g, l) \
    __builtin_amdgcn_global_load_lds((const __attribute__((address_space(1))) void*)(g), \
                                     (__attribute__((address_space(3))) void*)(l), 16, 0, 0)

// ------- prep: z<3: cast+transpose W (f32 [E][N] -> bf16 [N][E], Wq/Wv col-perm)
//               z==3: cast x -> bf16 row-major
__global__ __launch_bounds__(256) void prep_kernel(const float* __restrict__ x,
                                                   const float* __restrict__ W0,
                                                   const float* __restrict__ W1,
                                                   const float* __restrict__ W2,
                                                   short* __restrict__ WTall,
                                                   short* __restrict__ Xb) {
    if (blockIdx.z == 3) {
        const int gid = blockIdx.y * 16 + blockIdx.x;          // 0..255
        size_t base = (size_t)gid * 8192 + threadIdx.x * 8;
#pragma unroll
        for (int it = 0; it < 4; it++) {
            const float4* p = (const float4*)(x + base + it * 2048);
            float4 a = p[0], b = p[1];
            short8 v;
            v[0] = f2bf(a.x); v[1] = f2bf(a.y); v[2] = f2bf(a.z); v[3] = f2bf(a.w);
            v[4] = f2bf(b.x); v[5] = f2bf(b.y); v[6] = f2bf(b.z); v[7] = f2bf(b.w);
            *(short8*)(Xb + base + it * 2048) = v;
        }
        return;
    }
    const float* W = blockIdx.z == 0 ? W0 : (blockIdx.z == 1 ? W1 : W2);
    const bool perm = blockIdx.z < 2;
    short* WT = WTall + (size_t)blockIdx.z * NE * NE;

    __shared__ float tile[64][65];
    const int e0 = blockIdx.y * 64, j0 = blockIdx.x * 64;
    const int el = threadIdx.x & 63, grp = threadIdx.x >> 6;
    for (int i = grp; i < 64; i += 4)
        tile[i][el] = W[(size_t)(e0 + i) * NE + j0 + el];
    __syncthreads();
    for (int it = grp; it < 64; it += 4) {
        int j = j0 + it;
        int jp = perm ? ((j & 15) * 64 + (j >> 4)) : j;
        WT[(size_t)jp * NE + e0 + el] = f2bf(tile[el][it]);
    }
}

// ---------------- MFMA GEMM (global_load_lds + dbuf, 1 barrier/K-step) -----
// out[r][jp] = sum_e A[r][e] * WT[jp][e] + bias.  A,WT bf16.
// LDS: row-major [rows][BK] bf16, 16B chunk cp of row holds global chunk
// cp^(row&7) (inverse-swizzled SOURCE, linear dest; read applies same XOR).
// ZT_DUAL: grid-x spans 2*NE; c0>=NE half uses SWAPPED mfma operands ->
// D[jp][token], writes transposed Zt[jp][token] (+bias1, perm'd).
template <int BM, int BN, int BK, int THREADS, int LOG_GX, bool ZT_DUAL, bool PERM_BIAS, bool OUT_BF16>
__global__ __launch_bounds__(THREADS) void mfma_gemm_kernel(const short* __restrict__ A,
                                                            const short* __restrict__ WT,
                                                            const float* __restrict__ bias0,
                                                            const float* __restrict__ bias1,
                                                            void* __restrict__ out0,
                                                            short* __restrict__ outZt) {
    constexpr int WAVES = THREADS / 64;
    constexpr int WAVE_M = BM / (WAVES / 2), WAVE_N = BN / 2;
    constexpr int MR = WAVE_M / 16, NR = WAVE_N / 16;
    constexpr int ROWB = BK * 2;                      // LDS row bytes
    constexpr int CHM  = BK / 8 - 1;                  // chunk mask
    constexpr int ASZ = BM * BK, BSZ = BN * BK;       // shorts
    constexpr int SWA = BM * ROWB / (THREADS * 16);   // A DMA sweeps
    constexpr int SWB = BN * ROWB / (THREADS * 16);   // B DMA sweeps

    __shared__ __align__(16) short LB[2][ASZ + BSZ];
    const int tid = threadIdx.x;
    const int lane = tid & 63, wid = tid >> 6;

    // bijective XCD swizzle (nwg % 8 == 0)
    const int nwg = (1 << LOG_GX) * gridDim.y;
    const int bid = blockIdx.y * (1 << LOG_GX) + blockIdx.x;
    const int swz = (bid & 7) * (nwg >> 3) + (bid >> 3);
    const int r0 = (swz >> LOG_GX) * BM;
    const int c0 = (swz & ((1 << LOG_GX) - 1)) * BN;
    const int wr = (wid >> 1) * WAVE_M, wc = (wid & 1) * WAVE_N;
    const bool isZ = ZT_DUAL && (c0 >= NE);

    f32x4 acc[MR][NR];
#pragma unroll
    for (int m = 0; m < MR; m++)
#pragma unroll
        for (int n = 0; n < NR; n++) acc[m][n] = (f32x4){0.f, 0.f, 0.f, 0.f};

    // issue DMA for one K-tile into buffer `buf`
    auto stage = [&](int buf, int k0) {
        char* Ab = (char*)&LB[buf][0];
        char* Bb = (char*)&LB[buf][ASZ];
#pragma unroll
        for (int s = 0; s < SWA; s++) {
            int wb  = s * (THREADS * 16) + wid * 1024;    // wave-uniform LDS byte base
            int off = wb + lane * 16;                     // this lane's dest
            int row = off / ROWB;
            int c   = ((off >> 4) & CHM) ^ (row & 7);     // pre-swizzled source chunk
            GLOAD16(A + (size_t)(r0 + row) * NE + k0 + c * 8, Ab + wb);
        }
#pragma unroll
        for (int s = 0; s < SWB; s++) {
            int wb  = s * (THREADS * 16) + wid * 1024;
            int off = wb + lane * 16;
            int row = off / ROWB;
            int c   = ((off >> 4) & CHM) ^ (row & 7);
            GLOAD16(WT + (size_t)(c0 + row) * NE + k0 + c * 8, Bb + wb);
        }
    };

    stage(0, 0);
    __syncthreads();   // implicit vmcnt(0) drain: tile 0 resident

    int cur = 0;
    for (int k0 = 0; k0 < NE; k0 += BK) {
        if (k0 + BK < NE) stage(cur ^ 1, k0 + BK);   // DMA next tile under compute
        const char* Ab = (const char*)&LB[cur][0];
        const char* Bb = (const char*)&LB[cur][ASZ];
#pragma unroll
        for (int kk = 0; kk < BK / 32; kk++) {
            short8 af[MR], bf[NR];
            const int cidx = kk * 4 + (lane >> 4);
#pragma unroll
            for (int m = 0; m < MR; m++) {
                int row = wr + m * 16 + (lane & 15);
                af[m] = *(const short8*)(Ab + row * ROWB + ((cidx ^ (row & 7)) * 16));
            }
#pragma unroll
            for (int n = 0; n < NR; n++) {
                int row = wc + n * 16 + (lane & 15);
                bf[n] = *(const short8*)(Bb + row * ROWB + ((cidx ^ (row & 7)) * 16));
            }
            if (isZ) {
#pragma unroll
                for (int m = 0; m < MR; m++)
#pragma unroll
                    for (int n = 0; n < NR; n++)
                        acc[m][n] = __builtin_amdgcn_mfma_f32_16x16x32_bf16(bf[n], af[m], acc[m][n], 0, 0, 0);
            } else {
#pragma unroll
                for (int m = 0; m < MR; m++)
#pragma unroll
                    for (int n = 0; n < NR; n++)
                        acc[m][n] = __builtin_amdgcn_mfma_f32_16x16x32_bf16(af[m], bf[n], acc[m][n], 0, 0, 0);
            }
        }
        __syncthreads();   // drains vmcnt(0) (next tile landed) + all reads done
        cur ^= 1;
    }

    if (isZ) {
        // acc[m][n]: C-row = jp-local = wc + n*16 + (lane>>4)*4 + r
        //            C-col = token    = wr + m*16 + (lane&15)
        const int cb = c0 - NE;
        const int tok = r0 + wr + (lane & 15);
#pragma unroll
        for (int m = 0; m < MR; m++)
#pragma unroll
            for (int n = 0; n < NR; n++)
#pragma unroll
                for (int r = 0; r < 4; r++) {
                    int jp = cb + wc + n * 16 + (lane >> 4) * 4 + r;
                    float bb = bias1[(jp & 63) * 16 + (jp >> 6)];
                    outZt[(size_t)jp * NBT + tok + m * 16] = f2bf(acc[m][n][r] + bb);
                }
    } else {
        short* outS = (short*)out0;
        float* outF = (float*)out0;
#pragma unroll
        for (int m = 0; m < MR; m++)
#pragma unroll
            for (int n = 0; n < NR; n++) {
                int lc   = c0 + wc + n * 16 + (lane & 15);
                int bsrc = PERM_BIAS ? ((lc & 63) * 16 + (lc >> 6)) : lc;
                float bb = bias0[bsrc];
#pragma unroll
                for (int r = 0; r < 4; r++) {
                    int row = r0 + wr + m * 16 + (lane >> 4) * 4 + r;
                    float val = acc[m][n][r] + bb;
                    if (OUT_BF16) outS[(size_t)row * NE + lc] = f2bf(val);
                    else          outF[(size_t)row * NE + lc] = val;
                }
            }
    }
}

// ---------------- MFMA windowed attention ----------------------------------
// K staged via global_load_lds (clamped per-lane global addr, linear LDS);
// V^T reg-staged (boundary clamp). Everything else as verified.
__global__ __launch_bounds__(256) void attn_kernel(const short* __restrict__ Yb,
                                                   const short* __restrict__ Zt,
                                                   short* __restrict__ Mb) {
    __shared__ __align__(16) short KS[96][64];    // XOR-swizzled 16B chunks
    __shared__ __align__(16) short VT[64][96];    // [d][ws] linear
    __shared__ __align__(16) float SL[32][100];   // scores
    __shared__ __align__(16) short PL[32][104];   // probs bf16, zeroed outside band
    __shared__ float RED[32][17];                 // 0..7 max, 8..15 sum, 16 inv

    const int t0 = blockIdx.x * TT;
    const int h  = blockIdx.y;
    const int b  = blockIdx.z;
    const int tid = threadIdx.x;
    const int lane = tid & 63, wid = tid >> 6;

    // stage K (= Y rows, also Q) via DMA: 96 rows x 128B, 3 sweeps
    {
        char* Kb = (char*)&KS[0][0];
#pragma unroll
        for (int s = 0; s < 3; s++) {
            int wb  = s * 4096 + wid * 1024;
            int off = wb + lane * 16;
            int row = off >> 7;
            int c   = ((off >> 4) & 7) ^ (row & 7);   // pre-swizzled source chunk
            int ts = t0 - 32 + row;
            ts = ts < 0 ? 0 : (ts > NT - 1 ? NT - 1 : ts);
            GLOAD16(Yb + ((size_t)b * NT + ts) * NE + h * 64 + c * 8, Kb + wb);
        }
    }

    for (int u = tid; u < 416; u += 256)
        *(short8*)((short*)PL + u * 8) = (short8){0, 0, 0, 0, 0, 0, 0, 0};

    // stage V^T from Zt rows: 64 d-rows x 12 chunks of 8 (ws in [0,96))
    {
        const int d = tid >> 2, cbase = (tid & 3) * 3;
        const short* zr = Zt + (size_t)(h * 64 + d) * NBT + b * NT;
#pragma unroll
        for (int i = 0; i < 3; i++) {
            int ch = cbase + i;
            int s0 = t0 - 32 + ch * 8;
            short8 v;
            if (s0 >= 0 && s0 <= NT - 8) {
                v = *(const short8*)(zr + s0);
            } else {
#pragma unroll
                for (int j = 0; j < 8; j++) {
                    int ss = s0 + j;
                    ss = ss < 0 ? 0 : (ss > NT - 1 ? NT - 1 : ss);
                    v[j] = zr[ss];
                }
            }
            *(short8*)&VT[d][ch * 8] = v;
        }
    }
    __syncthreads();   // drains DMA (vmcnt) + ds_writes (lgkm)

    // QK^T: wave wid: m-frag mq = wid>>1, n-frags ntrio..+2 (s-cols)
    {
        const int mq = wid >> 1, ntrio = (wid & 1) * 3;
        f32x4 sacc[3];
#pragma unroll
        for (int ni = 0; ni < 3; ni++) sacc[ni] = (f32x4){0.f, 0.f, 0.f, 0.f};
#pragma unroll
        for (int ks = 0; ks < 2; ks++) {
            const int cidx = ks * 4 + (lane >> 4);
            int qrow = 32 + mq * 16 + (lane & 15);
            short8 af = *(const short8*)((char*)KS + qrow * 128 + ((cidx ^ (qrow & 7)) * 16));
#pragma unroll
            for (int ni = 0; ni < 3; ni++) {
                int srow = (ntrio + ni) * 16 + (lane & 15);
                short8 bf = *(const short8*)((char*)KS + srow * 128 + ((cidx ^ (srow & 7)) * 16));
                sacc[ni] = __builtin_amdgcn_mfma_f32_16x16x32_bf16(af, bf, sacc[ni], 0, 0, 0);
            }
        }
#pragma unroll
        for (int ni = 0; ni < 3; ni++)
#pragma unroll
            for (int r = 0; r < 4; r++)
                SL[mq * 16 + (lane >> 4) * 4 + r][(ntrio + ni) * 16 + (lane & 15)] =
                    sacc[ni][r] * 0.03125f;   // 1/sqrt(E)
    }
    __syncthreads();

    // banded softmax: thread (tl, oct) handles w = oct*8..+8, s = tl + w
    {
        const int tl = tid & (TT - 1), oct = tid >> 5;
        float sv[8];
#pragma unroll
        for (int wi = 0; wi < 8; wi++) sv[wi] = SL[tl][tl + oct * 8 + wi];
        float lmax = sv[0];
#pragma unroll
        for (int wi = 1; wi < 8; wi++) lmax = fmaxf(lmax, sv[wi]);
        RED[tl][oct] = lmax;
        __syncthreads();
        float gmax = RED[tl][0];
#pragma unroll
        for (int i = 1; i < 8; i++) gmax = fmaxf(gmax, RED[tl][i]);
        float lsum = 0.f;
#pragma unroll
        for (int wi = 0; wi < 8; wi++) {
            float e = __expf(sv[wi] - gmax);
            PL[tl][tl + oct * 8 + wi] = f2bf(e);
            lsum += e;
        }
        RED[tl][8 + oct] = lsum;
        __syncthreads();
        float gsum = RED[tl][8];
#pragma unroll
        for (int i = 9; i < 16; i++) gsum += RED[tl][i];
        if (oct == 0) RED[tl][16] = 1.0f / gsum;
    }
    __syncthreads();

    // PV: wave wid: m-frag mp = wid>>1 (rows), n-frags npair..+1 (d-cols)
    {
        const int mp = wid >> 1, npair = (wid & 1) * 2;
        f32x4 oacc[2];
#pragma unroll
        for (int ni = 0; ni < 2; ni++) oacc[ni] = (f32x4){0.f, 0.f, 0.f, 0.f};
#pragma unroll
        for (int ks = 0; ks < 3; ks++) {   // K = 96
            int prow = mp * 16 + (lane & 15);
            short8 pa = *(const short8*)((char*)PL + prow * 208 + ks * 64 + (lane >> 4) * 16);
#pragma unroll
            for (int ni = 0; ni < 2; ni++) {
                int d = (npair + ni) * 16 + (lane & 15);
                short8 bv = *(const short8*)((char*)VT + d * 192 + ks * 64 + (lane >> 4) * 16);
                oacc[ni] = __builtin_amdgcn_mfma_f32_16x16x32_bf16(pa, bv, oacc[ni], 0, 0, 0);
            }
        }
#pragma unroll
        for (int ni = 0; ni < 2; ni++) {
            int d = (npair + ni) * 16 + (lane & 15);
#pragma unroll
            for (int r = 0; r < 4; r++) {
                int tl = mp * 16 + (lane >> 4) * 4 + r;
                float inv = RED[tl][16];
                Mb[((size_t)b * NT + t0 + tl) * NE + h * 64 + d] = f2bf(oacc[ni][r] * inv);
            }
        }
    }
}

// ---------------------------------------------------------------------------
extern "C" void kernel_launch(void* const* d_in, const int* in_sizes, int n_in,
                              void* d_out, int out_size, void* d_ws, size_t ws_size,
                              hipStream_t stream) {
    const float* x  = (const float*)d_in[0];
    // d_in[1] = position_mask: unused (window gather computed analytically)
    const float* Wq = (const float*)d_in[2];
    const float* bq = (const float*)d_in[3];
    const float* Wv = (const float*)d_in[4];
    const float* bv = (const float*)d_in[5];
    const float* Wo = (const float*)d_in[6];
    const float* bo = (const float*)d_in[7];
    float* outp = (float*)d_out;

    // ws: WTa 6M (Wq,Wv,Wo) | Xb 4M | Yb 4M | Zt 4M | Mb 4M
    char* wsb = (char*)d_ws;
    short* WTa = (short*)(wsb);
    short* Xb  = (short*)(wsb + (6u << 20));
    short* Yb  = (short*)(wsb + (10u << 20));
    short* Zt  = (short*)(wsb + (14u << 20));
    short* Mb  = (short*)(wsb + (18u << 20));
    short* WTo = WTa + 2 * (size_t)NE * NE;

    prep_kernel<<<dim3(16, 16, 4), 256, 0, stream>>>(x, Wq, Wv, Wo, WTa, Xb);

    // fused Q/V projection: 128x128x128 tile, 8 waves; grid (16,16); Z half -> Zt
    mfma_gemm_kernel<128, 128, 128, 512, 4, true, true, true>
        <<<dim3(2 * NE / 128, NBT / 128), 512, 0, stream>>>(Xb, WTa, bq, bv, Yb, Zt);

    attn_kernel<<<dim3(NT / TT, NH, NB), 256, 0, stream>>>(Yb, Zt, Mb);

    // output projection: 64x128x128 tile, 4 waves -> grid (8,32)
    mfma_gemm_kernel<64, 128, 128, 256, 3, false, false, false>
        <<<dim3(NE / 128, NBT / 64), 256, 0, stream>>>(Mb, WTo, bo, nullptr, (void*)outp, nullptr);
}